// Round 1
// baseline (155.065 us; speedup 1.0000x reference)
//
#include <hip/hip_runtime.h>

#define RAD 8
#define HH 256
#define WW 256
#define NC 12
#define PS (HH*WW)
#define SCALE (255.0f/1023.0f)

// Region geometry for a 128x128 HR tile:
//  center LR rows/cols (mA/mB): <=36, mid (means/A/b): +8 halo = 52, raw: +16 = 68
#define NREG 68
#define NMID 52
#define NCEN 36
#define INP  69          // padded stride for input tiles   (69 mod 32 = 5, coprime)
#define HP   53          // padded stride for H6 and A/b    (53 mod 32 = 21, coprime)
#define CP   37          // padded stride for HA/HB, mA/mB  (37 mod 32 = 5, coprime)
#define HS   (NREG*HP)   // one H-boxed product plane = 3604 floats

// XCD-consistent swizzle for 768 blocks: each XCD gets 96 contiguous logical
// tiles so halo-sharing neighbor tiles hit the same XCD L2.
__device__ __forceinline__ int swz(int b) { return (b & 7) * 96 + (b >> 3); }

// ---------- K0: global sum of |l_a|+eps (deterministic two-stage) ----------
__global__ __launch_bounds__(256) void k_reduce(const float* __restrict__ la,
                                                float* __restrict__ partials) {
    int tid = threadIdx.x;
    __shared__ float ls[4];
    const float4* p4 = (const float4*)la;
    int base = blockIdx.x * 2048 + tid;
    float s = 0.f;
    #pragma unroll
    for (int i = 0; i < 8; i++) {
        float4 v = p4[base + i * 256];
        s += (fabsf(v.x) + 1e-12f) + (fabsf(v.y) + 1e-12f) +
             (fabsf(v.z) + 1e-12f) + (fabsf(v.w) + 1e-12f);
    }
    for (int off = 32; off > 0; off >>= 1) s += __shfl_down(s, off, 64);
    int lane = tid & 63, wid = tid >> 6;
    if (lane == 0) ls[wid] = s;
    __syncthreads();
    if (tid == 0) partials[blockIdx.x] = ls[0] + ls[1] + ls[2] + ls[3];
}

// ---------- K1: fully fused guided-filter + upsample, one block per 128x128 HR tile ----------
__global__ __launch_bounds__(512, 1) void k_fused(const float* __restrict__ la,
                                                  const float* __restrict__ lx,
                                                  const float* __restrict__ ly,
                                                  const float* __restrict__ hrx,
                                                  const float* __restrict__ partials,
                                                  float* __restrict__ out) {
    __shared__ float sIn[3 * NREG * INP];   // 14076 floats (56.3 KB)
    __shared__ float sH[6 * HS];            // 21624 floats (86.5 KB)
    __shared__ float sred[8];
    float* inA  = sIn;                      // [NREG][INP]  a = |la|+eps (0-padded)
    float* inX  = sIn + NREG * INP;         // lx (0-padded)
    float* inY  = sIn + 2 * NREG * INP;     // ly (0-padded)
    // aliases for later phases (each used only after the previous tenant is dead):
    float* Abuf = inA;                      // [NMID][HP]
    float* Bbuf = inX;                      // [NMID][HP]
    float* HAb  = inY;                      // [NMID][CP]
    float* HBb  = inY + NMID * CP;          // [NMID][CP]
    float* mAb  = sH;                       // [NCEN][CP]
    float* mBb  = sH + NCEN * CP;           // [NCEN][CP]

    int tid = threadIdx.x;
    int b  = swz(blockIdx.x);
    int p  = b >> 6;
    int t  = b & 63;
    int ti = t >> 3, tj = t & 7;
    int I0 = ti << 7, J0 = tj << 7;
    // exact integer floors with +/- slack vs the f32 per-pixel math
    int Lr0 = max(0, (I0 * 255) / 1023 - 1);
    int Lc0 = max(0, (J0 * 255) / 1023 - 1);

    // ---- phase 0: reduce 96 partials (result read after the phase-1 barrier)
    {
        float x = (tid < 96) ? partials[tid] : 0.f;
        for (int off = 32; off > 0; off >>= 1) x += __shfl_down(x, off, 64);
        if ((tid & 63) == 0) sred[tid >> 6] = x;
    }

    // ---- phase 1: load 68x68 raw region, zero-padded outside the image
    int r0g = Lr0 - 16, c0g = Lc0 - 16;
    const int plane = p * PS;
    for (unsigned idx = tid; idx < (unsigned)(NREG * NREG); idx += 512u) {
        int r = (int)(idx / 68u), c = (int)(idx % 68u);
        int gr = r0g + r, gc = c0g + c;
        float va = 0.f, vx = 0.f, vy = 0.f;
        if (gr >= 0 && gr < HH && gc >= 0 && gc < WW) {
            int off = plane + gr * WW + gc;
            va = fabsf(la[off]) + 1e-12f;
            vx = lx[off];
            vy = ly[off];
        }
        int w = r * INP + c;
        inA[w] = va; inX[w] = vx; inY[w] = vy;
    }
    __syncthreads();
    float invS = 1.0f / (sred[0] + sred[1] + sred[2] + sred[3] +
                         sred[4] + sred[5] + sred[6] + sred[7]);

    // ---- phase 2: horizontal 17-tap box of 6 products -> sH[6][68][52]
    // job = (row, col-strip of 13); lanes take consecutive rows (strides 69/53 coprime w/ 32)
    for (unsigned job = tid; job < 272u; job += 512u) {
        int r = (int)(job % 68u), strip = (int)(job / 68u);
        const float* rA = inA + r * INP;
        const float* rX = inX + r * INP;
        const float* rY = inY + r * INP;
        float* w0 = sH + r * HP;
        int c0 = strip * 13;
        float s0 = 0, s1 = 0, s2 = 0, s3 = 0, s4 = 0, s5 = 0;
        #pragma unroll
        for (int c = 0; c < 17; c++) {
            float a = rA[c0 + c], x = rX[c0 + c], y = rY[c0 + c];
            float ax = a * x, ay = a * y;
            s0 += a; s1 += ax; s2 += ay; s3 += a * ax; s4 += ax * ax; s5 += ax * ay;
        }
        w0[c0] = s0; w0[HS + c0] = s1; w0[2 * HS + c0] = s2;
        w0[3 * HS + c0] = s3; w0[4 * HS + c0] = s4; w0[5 * HS + c0] = s5;
        for (int jm = c0 + 1; jm <= c0 + 12; jm++) {
            float a = rA[jm + 16], x = rX[jm + 16], y = rY[jm + 16];
            float ax = a * x, ay = a * y;
            s0 += a; s1 += ax; s2 += ay; s3 += a * ax; s4 += ax * ax; s5 += ax * ay;
            a = rA[jm - 1]; x = rX[jm - 1]; y = rY[jm - 1];
            ax = a * x; ay = a * y;
            s0 -= a; s1 -= ax; s2 -= ay; s3 -= a * ax; s4 -= ax * ax; s5 -= ax * ay;
            w0[jm] = s0; w0[HS + jm] = s1; w0[2 * HS + jm] = s2;
            w0[3 * HS + jm] = s3; w0[4 * HS + jm] = s4; w0[5 * HS + jm] = s5;
        }
    }
    __syncthreads();

    // ---- phase 3: vertical box + pointwise A,b -> Abuf/Bbuf[52][53]
    // job = (col, row-strip of 13); lanes take consecutive cols (addresses consecutive)
    for (unsigned job = tid; job < 208u; job += 512u) {
        int jm = (int)(job % 52u), strip = (int)(job / 52u);
        int gjC = Lc0 - 8 + jm;
        bool cok = (gjC >= 0) && (gjC < WW);
        float cxw = (float)(min(gjC + RAD, WW - 1) - max(gjC - RAD, 0) + 1);
        const float* colp = sH + jm;
        int r0 = strip * 13;
        float s0 = 0, s1 = 0, s2 = 0, s3 = 0, s4 = 0, s5 = 0;
        #pragma unroll
        for (int d = 0; d < 17; d++) {
            int o = (r0 + d) * HP;
            s0 += colp[o];          s1 += colp[HS + o];     s2 += colp[2 * HS + o];
            s3 += colp[3 * HS + o]; s4 += colp[4 * HS + o]; s5 += colp[5 * HS + o];
        }
        for (int im = r0; im < r0 + 13; im++) {
            if (im > r0) {
                int oa = (im + 16) * HP, os = (im - 1) * HP;
                s0 += colp[oa] - colp[os];
                s1 += colp[HS + oa] - colp[HS + os];
                s2 += colp[2 * HS + oa] - colp[2 * HS + os];
                s3 += colp[3 * HS + oa] - colp[3 * HS + os];
                s4 += colp[4 * HS + oa] - colp[4 * HS + os];
                s5 += colp[5 * HS + oa] - colp[5 * HS + os];
            }
            int giR = Lr0 - 8 + im;
            float Av = 0.f, bv = 0.f;
            if (cok && giR >= 0 && giR < HH) {
                float cyw = (float)(min(giR + RAD, HH - 1) - max(giR - RAD, 0) + 1);
                float Nv = cxw * cyw, invN = 1.0f / Nv;
                float m_a = s0 * invN, m_ax = s1 * invN, m_ay = s2 * invN;
                float m_tax = s3 * invN * invS;
                float m_a2x2 = s4 * invN, m_a2xy = s5 * invN;
                float tempv = fabsf(m_a2x2 - Nv * m_tax * m_ax);
                Av = (m_a2xy - Nv * m_tax * m_ay) / (tempv + 1e-8f);
                bv = (m_ay - Av * m_ax) / m_a;
            }
            Abuf[im * HP + jm] = Av;   // out-of-image rows/cols stay exactly 0
            Bbuf[im * HP + jm] = bv;
        }
    }
    __syncthreads();

    // ---- phase 4: horizontal box of A,b -> HAb/HBb[52][37]
    for (unsigned job = tid; job < 208u; job += 512u) {
        int row   = (int)(job % 52u);
        int which = (int)((job / 52u) & 1u);
        int strip = (int)(job / 104u);
        const float* rp = (which ? Bbuf : Abuf) + row * HP;
        float* dst = (which ? HBb : HAb) + row * CP;
        int c0 = strip * 18;
        float sum = 0.f;
        #pragma unroll
        for (int c = 0; c < 17; c++) sum += rp[c0 + c];
        dst[c0] = sum;
        for (int jc = c0 + 1; jc < c0 + 18; jc++) {
            sum += rp[jc + 16] - rp[jc - 1];
            dst[jc] = sum;
        }
    }
    __syncthreads();

    // ---- phase 5: vertical box of HA,HB, divide by N -> mAb/mBb[36][37]
    for (unsigned job = tid; job < 144u; job += 512u) {
        int colc  = (int)(job % 36u);
        int which = (int)((job / 36u) & 1u);
        int strip = (int)(job / 72u);
        const float* src = which ? HBb : HAb;
        float* dst = which ? mBb : mAb;
        int gjC = Lc0 + colc;
        float cxw = (float)(min(gjC + RAD, WW - 1) - max(gjC - RAD, 0) + 1);
        int r0 = strip * 18;
        float sum = 0.f;
        #pragma unroll
        for (int d = 0; d < 17; d++) sum += src[(r0 + d) * CP + colc];
        for (int ic = r0; ic < r0 + 18; ic++) {
            if (ic > r0) sum += src[(ic + 16) * CP + colc] - src[(ic - 1) * CP + colc];
            int giR = Lr0 + ic;
            float cyw = (float)(min(giR + RAD, HH - 1) - max(giR - RAD, 0) + 1);
            dst[ic * CP + colc] = sum / (cxw * cyw);
        }
    }
    __syncthreads();

    // ---- phase 6: bilinear upsample from LDS + fuse with hr_x (verbatim resize math)
    {
        int col4 = tid & 31;                 // float4 column within the tile (fixed/thread)
        int rb   = tid >> 5;                 // 0..15
        int J4 = (J0 >> 2) + col4;           // global float4 column
        int Jp = J4 << 2;                    // global pixel column
        int xb = (int)((float)Jp * SCALE);
        int i1 = min(xb + 1, WW - 1), i2 = min(xb + 2, WW - 1);
        int lxb = xb - Lc0, li1 = i1 - Lc0, li2 = i2 - Lc0;   // all in [0,35]
        float wxv[4]; bool hs[4];
        #pragma unroll
        for (int k = 0; k < 4; k++) {
            float xsk = (float)(Jp + k) * SCALE;
            int x0 = (int)xsk;
            wxv[k] = xsk - (float)x0;
            hs[k] = (x0 > xb);
        }
        const float4* h4 = (const float4*)hrx;
        float4* o4 = (float4*)out;
        int planeHR = p * 262144;            // 1024*256 float4 per plane
        #pragma unroll
        for (int it = 0; it < 8; it++) {
            int row = (it << 4) + rb;        // 0..127
            int I = I0 + row;
            float ysf = (float)I * SCALE;
            int y0 = (int)ysf;
            float wy = ysf - (float)y0;
            int y1 = min(y0 + 1, HH - 1);
            int ly0 = y0 - Lr0, ly1 = y1 - Lr0;   // in [0,35]
            const float* a0p = mAb + ly0 * CP;
            const float* a1p = mAb + ly1 * CP;
            const float* b0p = mBb + ly0 * CP;
            const float* b1p = mBb + ly1 * CP;
            float A0a = a0p[lxb], A0b = a0p[li1], A0c = a0p[li2];
            float A1a = a1p[lxb], A1b = a1p[li1], A1c = a1p[li2];
            float B0a = b0p[lxb], B0b = b0p[li1], B0c = b0p[li2];
            float B1a = b1p[lxb], B1b = b1p[li1], B1c = b1p[li2];
            int hidx = planeHR + I * 256 + J4;
            float4 h = h4[hidx];
            float hv[4] = {h.x, h.y, h.z, h.w};
            float ov[4];
            float omwy = 1.0f - wy;
            #pragma unroll
            for (int k = 0; k < 4; k++) {
                bool hb = hs[k];
                float Alo0 = hb ? A0b : A0a, Ahi0 = hb ? A0c : A0b;
                float Alo1 = hb ? A1b : A1a, Ahi1 = hb ? A1c : A1b;
                float Blo0 = hb ? B0b : B0a, Bhi0 = hb ? B0c : B0b;
                float Blo1 = hb ? B1b : B1a, Bhi1 = hb ? B1c : B1b;
                float wx = wxv[k], omwx = 1.0f - wx;
                float Ar0 = Alo0 * omwx + Ahi0 * wx;
                float Ar1 = Alo1 * omwx + Ahi1 * wx;
                float Br0 = Blo0 * omwx + Bhi0 * wx;
                float Br1 = Blo1 * omwx + Bhi1 * wx;
                float Avv = Ar0 * omwy + Ar1 * wy;
                float Bvv = Br0 * omwy + Br1 * wy;
                ov[k] = Avv * hv[k] + Bvv;
            }
            float4 o; o.x = ov[0]; o.y = ov[1]; o.z = ov[2]; o.w = ov[3];
            o4[hidx] = o;
        }
    }
}

extern "C" void kernel_launch(void* const* d_in, const int* in_sizes, int n_in,
                              void* d_out, int out_size, void* d_ws, size_t ws_size,
                              hipStream_t stream) {
    const float* lr_x = (const float*)d_in[0];
    const float* lr_y = (const float*)d_in[1];
    const float* hr_x = (const float*)d_in[2];
    const float* l_a  = (const float*)d_in[3];
    float* partials = (float*)d_ws;   // 96 floats

    k_reduce<<<96, 256, 0, stream>>>(l_a, partials);
    k_fused<<<768, 512, 0, stream>>>(l_a, lr_x, lr_y, hr_x, partials, (float*)d_out);
}